// Round 10
// baseline (143.218 us; speedup 1.0000x reference)
//
#include <hip/hip_runtime.h>

typedef short short8 __attribute__((ext_vector_type(8)));
typedef float f32x4 __attribute__((ext_vector_type(4)));

#define NTOK (8 * 16 * 32 * 32)  // 131072 tokens
#define NE 1024
#define ED 64
#define TPB 256
#define MBLK 128                 // tokens per block = 4 waves x 32
#define NMF 2                    // m-frags per wave (32 tokens) — 4 waves/SIMD TLP
#define WKEY (1 << 19)           // candidate window: 7.8e-3 in dist units
                                 // (~10.5 sigma of the pure-bf16 approx error)
#define SCALE (-131072.0f)       // -2^17: exact po2 scale — applied to B ONLY

__device__ __forceinline__ unsigned short bf16_rtne(float f) {
    unsigned u = __float_as_uint(f);
    return (unsigned short)((u + 0x7FFFu + ((u >> 16) & 1u)) >> 16);
}

// EXACT distance — identical structure/order to the R1 kernel (absmax 0 vs numpy).
__device__ float exact_dist(const float* __restrict__ z, const float* __restrict__ emb,
                            int t, int e) {
    const float* zt = z + (size_t)t * ED;
    const float* ep = emb + (size_t)e * ED;
    float r0 = 0.f, r1 = 0.f, r2 = 0.f, r3 = 0.f;
    float r4 = 0.f, r5 = 0.f, r6 = 0.f, r7 = 0.f;
    for (int d = 0; d < ED; d += 8) {
        r0 += zt[d + 0] * zt[d + 0];
        r1 += zt[d + 1] * zt[d + 1];
        r2 += zt[d + 2] * zt[d + 2];
        r3 += zt[d + 3] * zt[d + 3];
        r4 += zt[d + 4] * zt[d + 4];
        r5 += zt[d + 5] * zt[d + 5];
        r6 += zt[d + 6] * zt[d + 6];
        r7 += zt[d + 7] * zt[d + 7];
    }
    float s1 = ((r0 + r1) + (r2 + r3)) + ((r4 + r5) + (r6 + r7));
    float q0 = 0.f, q1 = 0.f, q2 = 0.f, q3 = 0.f;
    float q4 = 0.f, q5 = 0.f, q6 = 0.f, q7 = 0.f;
    for (int d = 0; d < ED; d += 8) {
        float v0 = ep[d + 0], v1 = ep[d + 1], v2 = ep[d + 2], v3 = ep[d + 3];
        float v4 = ep[d + 4], v5 = ep[d + 5], v6 = ep[d + 6], v7 = ep[d + 7];
        q0 += v0 * v0; q1 += v1 * v1; q2 += v2 * v2; q3 += v3 * v3;
        q4 += v4 * v4; q5 += v5 * v5; q6 += v6 * v6; q7 += v7 * v7;
    }
    float s2 = ((q0 + q1) + (q2 + q3)) + ((q4 + q5) + (q6 + q7));
    float a0 = 0.f, a1 = 0.f, a2 = 0.f, a3 = 0.f;
    for (int d = 0; d < ED; d += 4) {
        a0 = fmaf(zt[d + 0], ep[d + 0], a0);
        a1 = fmaf(zt[d + 1], ep[d + 1], a1);
        a2 = fmaf(zt[d + 2], ep[d + 2], a2);
        a3 = fmaf(zt[d + 3], ep[d + 3], a3);
    }
    float g = (a0 + a1) + (a2 + a3);
    return (s1 + s2) - 2.0f * g;
}

// ---- prep: B-fragments (bf16 HI only, -2^17-scaled, MFMA order) + scaled s2 ----
__global__ __launch_bounds__(128) void vq_prep(
    const float* __restrict__ emb,
    unsigned short* __restrict__ bfH,
    float* __restrict__ s2s)
{
    const int f = blockIdx.x * 128 + threadIdx.x;  // 0..8191 fragment id
    const int col = f & 15;
    const int quad = (f >> 4) & 3;
    const int kb = (f >> 6) & 1;
    const int nt = f >> 7;
    const int e = nt * 16 + col;
    const int k0 = kb * 32 + quad * 8;

    const float* p = emb + (size_t)e * ED + k0;
    float4 v0 = *(const float4*)p;
    float4 v1 = *(const float4*)(p + 4);
    float vs[8] = {v0.x, v0.y, v0.z, v0.w, v1.x, v1.y, v1.z, v1.w};
    short8 h;
#pragma unroll
    for (int j = 0; j < 8; ++j) {
        float x = vs[j] * SCALE;              // exact po2 scaling (B side only!)
        h[j] = (short)bf16_rtne(x);
    }
    *(short8*)&bfH[(size_t)f * 8] = h;

    if (f < 4096) {
        const int row = f >> 2;
        const float4* rp = (const float4*)(emb + (size_t)row * ED + (f & 3) * 16);
        float4 a = rp[0], b = rp[1], c = rp[2], d = rp[3];
        float s = a.x * a.x + a.y * a.y + a.z * a.z + a.w * a.w
                + b.x * b.x + b.y * b.y + b.z * b.z + b.w * b.w
                + c.x * c.x + c.y * c.y + c.z * c.z + c.w * c.w
                + d.x * d.x + d.y * d.y + d.z * d.z + d.w * d.w;
        s += __shfl_xor(s, 1);
        s += __shfl_xor(s, 2);
        if ((f & 3) == 0) s2s[row] = s * 65536.0f;
    }
}

// ---- main: R9 numeric scheme (pure bf16, 8 MFMA per 64 tokens) at DOUBLE
//      occupancy. R9 showed wall/SIMD-iter ~1900 cyc vs ~800 cyc of issue —
//      latency-bound at 2 waves/SIMD. NMF=2 halves tokens/wave -> 4 waves/SIMD
//      with identical total MFMA + key-update work per SIMD (4x32 == 2x64
//      tokens/SIMD-iter); only loop overhead and B reg-delivery (4 B/pair,
//      ~16us chip-wide through L2) double — both hidden by the added TLP. ----
__global__ void __launch_bounds__(TPB) vq_main(
    const float* __restrict__ z,
    const float* __restrict__ emb,
    const unsigned short* __restrict__ bfH,
    const float* __restrict__ s2s_g,
    float* __restrict__ zq_out,
    float* __restrict__ idx_out)
{
    __shared__ float s2L[NE];
    __shared__ int idx_lds[MBLK];

    const int tid = threadIdx.x;
    const int lane = tid & 63;
    const int wv = __builtin_amdgcn_readfirstlane(tid >> 6);
    const int col = lane & 15;
    const int quad = lane >> 4;
    const int blockTok = blockIdx.x * MBLK;

    for (int i = tid; i < NE; i += TPB) s2L[i] = s2s_g[i];

    // ---- A-fragments: 32 tokens per wave (2 m-frags), bf16 hi only, UNSCALED ----
    short8 Ah[NMF][2];
#pragma unroll
    for (int mf = 0; mf < NMF; ++mf) {
#pragma unroll
        for (int kf = 0; kf < 2; ++kf) {
            const float* zp = z + (size_t)(blockTok + wv * 32 + mf * 16 + col) * ED
                              + kf * 32 + quad * 8;
            float4 v0 = *(const float4*)zp;
            float4 v1 = *(const float4*)(zp + 4);
            float vs[8] = {v0.x, v0.y, v0.z, v0.w, v1.x, v1.y, v1.z, v1.w};
            short8 h;
#pragma unroll
            for (int j = 0; j < 8; ++j) h[j] = (short)bf16_rtne(vs[j]);
            Ah[mf][kf] = h;
        }
    }

    int aK[NMF][4], bK[NMF][4];
#pragma unroll
    for (int mf = 0; mf < NMF; ++mf)
#pragma unroll
        for (int r = 0; r < 4; ++r) { aK[mf][r] = 0x7FFFFFFF; bK[mf][r] = 0x7FFFFFFF; }

    // B-fragment stream: per nt-slice, 128 fragments of 16B; lane's frags are
    // u4[nt*128 + lane] (k-frag 0) and u4[nt*128 + 64 + lane] (k-frag 1).
    const uint4* u4H = (const uint4*)bfH;

    // prologue: load slice 0
    uint4 cB0 = u4H[lane];
    uint4 cB1 = u4H[64 + lane];

    __syncthreads();  // s2L ready (only barrier before the epilogue)

    for (int nt = 0; nt < 64; ++nt) {
        // prefetch next slice (wrap: redundant re-load of slice 0, never consumed)
        const int nb = (((nt + 1) & 63) << 7) + lane;
        uint4 nB0 = u4H[nb];
        uint4 nB1 = u4H[nb + 64];

        short8 Bh0 = __builtin_bit_cast(short8, cB0);
        short8 Bh1 = __builtin_bit_cast(short8, cB1);

        const float s2v = s2L[nt * 16 + col];
        const int e = nt * 16 + col;

        f32x4 cc[NMF];
        __builtin_amdgcn_s_setprio(1);
#pragma unroll
        for (int mf = 0; mf < NMF; ++mf) {
            f32x4 c0 = {s2v, s2v, s2v, s2v};  // acc = s2*2^16 + A·(-2^17 e) = 2^16(s2-2g)
            c0 = __builtin_amdgcn_mfma_f32_16x16x32_bf16(Ah[mf][0], Bh0, c0, 0, 0, 0);
            c0 = __builtin_amdgcn_mfma_f32_16x16x32_bf16(Ah[mf][1], Bh1, c0, 0, 0, 0);
            cc[mf] = c0;
        }
        __builtin_amdgcn_s_setprio(0);

#pragma unroll
        for (int mf = 0; mf < NMF; ++mf) {
#pragma unroll
            for (int r = 0; r < 4; ++r) {
                // key = int(cc)*1024 + e — int(cc) <= ~2^17 fits i24 exactly
                int ci = (int)cc[mf][r];
                int key;
                asm("v_mad_i32_i24 %0, %1, %2, %3"
                    : "=v"(key) : "v"(ci), "s"(1024), "v"(e));
                const int a0 = aK[mf][r];
                int t1 = min(a0, key);
                // bK' = min(bK, max(a0, key)) == med3(a0, bK, key) since a0<=bK
                int med;
                asm("v_med3_i32 %0, %1, %2, %3"
                    : "=v"(med) : "v"(a0), "v"(bK[mf][r]), "v"(key));
                bK[mf][r] = med;
                aK[mf][r] = t1;
            }
        }

        cB0 = nB0; cB1 = nB1;
    }

    // ---- phase B: resolve argmin per token (16-lane groups) ----
#pragma unroll
    for (int mf = 0; mf < NMF; ++mf) {
#pragma unroll
        for (int r = 0; r < 4; ++r) {
            const int a0 = aK[mf][r], b0 = bK[mf][r];
            int A = a0, B = b0;
#pragma unroll
            for (int off = 1; off < 16; off <<= 1) {
                int A2 = __shfl_xor(A, off);
                int B2 = __shfl_xor(B, off);
                int lo = min(A, A2), hi = max(A, A2);
                B = min(min(B, B2), hi);
                A = lo;
            }
            int winner = A & 1023;
            if (B - A <= WKEY) {  // contested: exact fp32 re-check of candidates
                const int t = blockTok + wv * 32 + mf * 16 + quad * 4 + r;
                float dbest = 3.4e38f;
                int ibest = 1 << 30;
                if (a0 <= A + WKEY) {
                    int e = a0 & 1023;
                    float d = exact_dist(z, emb, t, e);
                    if (d < dbest || (d == dbest && e < ibest)) { dbest = d; ibest = e; }
                }
                if (b0 <= A + WKEY) {
                    int e = b0 & 1023;
                    float d = exact_dist(z, emb, t, e);
                    if (d < dbest || (d == dbest && e < ibest)) { dbest = d; ibest = e; }
                }
#pragma unroll
                for (int off = 1; off < 16; off <<= 1) {
                    float d2 = __shfl_xor(dbest, off);
                    int i2 = __shfl_xor(ibest, off);
                    if (d2 < dbest || (d2 == dbest && i2 < ibest)) { dbest = d2; ibest = i2; }
                }
                winner = ibest;
            }
            if (col == 0) idx_lds[wv * 32 + mf * 16 + quad * 4 + r] = winner;
        }
    }

    __syncthreads();

    // ---- outputs ----
    if (tid < MBLK) idx_out[blockTok + tid] = (float)idx_lds[tid];
    const float4* emb_f4 = (const float4*)emb;
    float4* zq_f4 = (float4*)zq_out;
#pragma unroll
    for (int i = 0; i < MBLK * 16 / TPB; ++i) {  // 8 iters
        int item = tid + i * TPB;
        int tl = item >> 4, f4 = item & 15;
        int wi = idx_lds[tl];
        zq_f4[(size_t)(blockTok + tl) * 16 + f4] = emb_f4[(size_t)wi * 16 + f4];
    }
}

extern "C" void kernel_launch(void* const* d_in, const int* in_sizes, int n_in,
                              void* d_out, int out_size, void* d_ws, size_t ws_size,
                              hipStream_t stream) {
    const float* z = (const float*)d_in[0];
    const float* emb = (const float*)d_in[1];
    float* out = (float*)d_out;
    float* zq = out;                       // 131072*64 floats
    float* idx = out + (size_t)NTOK * ED;  // 131072 floats

    // ws layout: s2s (4KB) | bfH (128KB)
    char* ws = (char*)d_ws;
    float* s2s = (float*)ws;
    unsigned short* bfH = (unsigned short*)(ws + 4096);

    vq_prep<<<64, 128, 0, stream>>>(emb, bfH, s2s);
    vq_main<<<NTOK / MBLK, TPB, 0, stream>>>(z, emb, bfH, s2s, zq, idx);
}

// Round 11
// 129.911 us; speedup vs baseline: 1.1024x; 1.1024x over previous
//
#include <hip/hip_runtime.h>

typedef short short8 __attribute__((ext_vector_type(8)));
typedef float f32x4 __attribute__((ext_vector_type(4)));

#define NTOK (8 * 16 * 32 * 32)  // 131072 tokens
#define NE 1024
#define ED 64
#define TPB 256
#define MBLK 256                 // tokens per block = 4 waves x 64
#define NMF 4                    // m-frags per wave (64 tokens)
#define WKEY (1 << 19)           // candidate window: 7.8e-3 in dist units
#define SCALE (-131072.0f)       // -2^17: exact po2 scale — applied to B ONLY

__device__ __forceinline__ unsigned short bf16_rtne(float f) {
    unsigned u = __float_as_uint(f);
    return (unsigned short)((u + 0x7FFFu + ((u >> 16) & 1u)) >> 16);
}

// EXACT distance — identical structure/order to the R1 kernel (absmax 0 vs numpy).
__device__ float exact_dist(const float* __restrict__ z, const float* __restrict__ emb,
                            int t, int e) {
    const float* zt = z + (size_t)t * ED;
    const float* ep = emb + (size_t)e * ED;
    float r0 = 0.f, r1 = 0.f, r2 = 0.f, r3 = 0.f;
    float r4 = 0.f, r5 = 0.f, r6 = 0.f, r7 = 0.f;
    for (int d = 0; d < ED; d += 8) {
        r0 += zt[d + 0] * zt[d + 0];
        r1 += zt[d + 1] * zt[d + 1];
        r2 += zt[d + 2] * zt[d + 2];
        r3 += zt[d + 3] * zt[d + 3];
        r4 += zt[d + 4] * zt[d + 4];
        r5 += zt[d + 5] * zt[d + 5];
        r6 += zt[d + 6] * zt[d + 6];
        r7 += zt[d + 7] * zt[d + 7];
    }
    float s1 = ((r0 + r1) + (r2 + r3)) + ((r4 + r5) + (r6 + r7));
    float q0 = 0.f, q1 = 0.f, q2 = 0.f, q3 = 0.f;
    float q4 = 0.f, q5 = 0.f, q6 = 0.f, q7 = 0.f;
    for (int d = 0; d < ED; d += 8) {
        float v0 = ep[d + 0], v1 = ep[d + 1], v2 = ep[d + 2], v3 = ep[d + 3];
        float v4 = ep[d + 4], v5 = ep[d + 5], v6 = ep[d + 6], v7 = ep[d + 7];
        q0 += v0 * v0; q1 += v1 * v1; q2 += v2 * v2; q3 += v3 * v3;
        q4 += v4 * v4; q5 += v5 * v5; q6 += v6 * v6; q7 += v7 * v7;
    }
    float s2 = ((q0 + q1) + (q2 + q3)) + ((q4 + q5) + (q6 + q7));
    float a0 = 0.f, a1 = 0.f, a2 = 0.f, a3 = 0.f;
    for (int d = 0; d < ED; d += 4) {
        a0 = fmaf(zt[d + 0], ep[d + 0], a0);
        a1 = fmaf(zt[d + 1], ep[d + 1], a1);
        a2 = fmaf(zt[d + 2], ep[d + 2], a2);
        a3 = fmaf(zt[d + 3], ep[d + 3], a3);
    }
    float g = (a0 + a1) + (a2 + a3);
    return (s1 + s2) - 2.0f * g;
}

// ---- prep: B-fragments (bf16 HI only, -2^17-scaled, MFMA order) + scaled s2 ----
__global__ __launch_bounds__(128) void vq_prep(
    const float* __restrict__ emb,
    unsigned short* __restrict__ bfH,
    float* __restrict__ s2s)
{
    const int f = blockIdx.x * 128 + threadIdx.x;  // 0..8191 fragment id
    const int col = f & 15;
    const int quad = (f >> 4) & 3;
    const int kb = (f >> 6) & 1;
    const int nt = f >> 7;
    const int e = nt * 16 + col;
    const int k0 = kb * 32 + quad * 8;

    const float* p = emb + (size_t)e * ED + k0;
    float4 v0 = *(const float4*)p;
    float4 v1 = *(const float4*)(p + 4);
    float vs[8] = {v0.x, v0.y, v0.z, v0.w, v1.x, v1.y, v1.z, v1.w};
    short8 h;
#pragma unroll
    for (int j = 0; j < 8; ++j) {
        float x = vs[j] * SCALE;              // exact po2 scaling (B side only!)
        h[j] = (short)bf16_rtne(x);
    }
    *(short8*)&bfH[(size_t)f * 8] = h;

    if (f < 4096) {
        const int row = f >> 2;
        const float4* rp = (const float4*)(emb + (size_t)row * ED + (f & 3) * 16);
        float4 a = rp[0], b = rp[1], c = rp[2], d = rp[3];
        float s = a.x * a.x + a.y * a.y + a.z * a.z + a.w * a.w
                + b.x * b.x + b.y * b.y + b.z * b.z + b.w * b.w
                + c.x * c.x + c.y * c.y + c.z * c.z + c.w * c.w
                + d.x * d.x + d.y * d.y + d.z * d.z + d.w * d.w;
        s += __shfl_xor(s, 1);
        s += __shfl_xor(s, 2);
        if ((f & 3) == 0) s2s[row] = s * 65536.0f;
    }
}

// ---- main: R9 numerics (pure bf16, 8 MFMA / 64 tokens / slice) with the
//      nt-loop UNROLLED x2. R9 vs R10 showed cost scales with wave-iteration
//      count (fixed ~1000cyc overhead/iter: loop ctl, prefetch addr chain,
//      s2 ds_read latency, waitcnt) — so amortize: one iteration processes
//      2 slices (16 MFMA, 32 key updates) with one prefetch/control round,
//      and the s2 seeds are register-prefetched one iteration ahead (LDS
//      latency off the MFMA critical path). Numerics bit-identical to R9. ----
__global__ void __launch_bounds__(TPB) vq_main(
    const float* __restrict__ z,
    const float* __restrict__ emb,
    const unsigned short* __restrict__ bfH,
    const float* __restrict__ s2s_g,
    float* __restrict__ zq_out,
    float* __restrict__ idx_out)
{
    __shared__ float s2L[NE];
    __shared__ int idx_lds[MBLK];

    const int tid = threadIdx.x;
    const int lane = tid & 63;
    const int wv = __builtin_amdgcn_readfirstlane(tid >> 6);
    const int col = lane & 15;
    const int quad = lane >> 4;
    const int blockTok = blockIdx.x * MBLK;

    for (int i = tid; i < NE; i += TPB) s2L[i] = s2s_g[i];

    // ---- A-fragments: 64 tokens per wave (4 m-frags), bf16 hi only, UNSCALED ----
    short8 Ah[NMF][2];
#pragma unroll
    for (int mf = 0; mf < NMF; ++mf) {
#pragma unroll
        for (int kf = 0; kf < 2; ++kf) {
            const float* zp = z + (size_t)(blockTok + wv * 64 + mf * 16 + col) * ED
                              + kf * 32 + quad * 8;
            float4 v0 = *(const float4*)zp;
            float4 v1 = *(const float4*)(zp + 4);
            float vs[8] = {v0.x, v0.y, v0.z, v0.w, v1.x, v1.y, v1.z, v1.w};
            short8 h;
#pragma unroll
            for (int j = 0; j < 8; ++j) h[j] = (short)bf16_rtne(vs[j]);
            Ah[mf][kf] = h;
        }
    }

    int aK[NMF][4], bK[NMF][4];
#pragma unroll
    for (int mf = 0; mf < NMF; ++mf)
#pragma unroll
        for (int r = 0; r < 4; ++r) { aK[mf][r] = 0x7FFFFFFF; bK[mf][r] = 0x7FFFFFFF; }

    // B-fragment stream: per nt-slice, 128 fragments of 16B; lane's frags are
    // u4[nt*128 + lane] (k-frag 0) and u4[nt*128 + 64 + lane] (k-frag 1).
    const uint4* u4H = (const uint4*)bfH;

    // prologue: load slices 0 and 1
    uint4 cB0a = u4H[lane];
    uint4 cB1a = u4H[64 + lane];
    uint4 cB0b = u4H[128 + lane];
    uint4 cB1b = u4H[192 + lane];

    __syncthreads();  // s2L ready (only barrier before the epilogue)

    // s2 seeds for slices 0,1 (register-resident; refreshed one iter ahead)
    float s2c0 = s2L[col];
    float s2c1 = s2L[16 + col];

    for (int nt = 0; nt < 64; nt += 2) {
        // prefetch slices nt+2, nt+3 (wrap: redundant, never consumed)
        const int nb2 = (((nt + 2) & 63) << 7) + lane;
        const int nb3 = (((nt + 3) & 63) << 7) + lane;
        uint4 nB0a = u4H[nb2];
        uint4 nB1a = u4H[nb2 + 64];
        uint4 nB0b = u4H[nb3];
        uint4 nB1b = u4H[nb3 + 64];
        // prefetch next pair's s2 seeds (LDS latency hidden under this iter)
        float s2n0 = s2L[((nt + 2) & 63) * 16 + col];
        float s2n1 = s2L[((nt + 3) & 63) * 16 + col];

        short8 BhA0 = __builtin_bit_cast(short8, cB0a);
        short8 BhA1 = __builtin_bit_cast(short8, cB1a);
        short8 BhB0 = __builtin_bit_cast(short8, cB0b);
        short8 BhB1 = __builtin_bit_cast(short8, cB1b);

        const int e0 = nt * 16 + col;
        const int e1 = e0 + 16;

        f32x4 ccA[NMF], ccB[NMF];
        __builtin_amdgcn_s_setprio(1);
#pragma unroll
        for (int mf = 0; mf < NMF; ++mf) {
            f32x4 c0 = {s2c0, s2c0, s2c0, s2c0};
            c0 = __builtin_amdgcn_mfma_f32_16x16x32_bf16(Ah[mf][0], BhA0, c0, 0, 0, 0);
            c0 = __builtin_amdgcn_mfma_f32_16x16x32_bf16(Ah[mf][1], BhA1, c0, 0, 0, 0);
            ccA[mf] = c0;
        }
#pragma unroll
        for (int mf = 0; mf < NMF; ++mf) {
            f32x4 c1 = {s2c1, s2c1, s2c1, s2c1};
            c1 = __builtin_amdgcn_mfma_f32_16x16x32_bf16(Ah[mf][0], BhB0, c1, 0, 0, 0);
            c1 = __builtin_amdgcn_mfma_f32_16x16x32_bf16(Ah[mf][1], BhB1, c1, 0, 0, 0);
            ccB[mf] = c1;
        }
        __builtin_amdgcn_s_setprio(0);

        // key updates for slice nt then nt+1 — same per-slice order as R9
#pragma unroll
        for (int mf = 0; mf < NMF; ++mf) {
#pragma unroll
            for (int r = 0; r < 4; ++r) {
                int ci = (int)ccA[mf][r];
                int key;
                asm("v_mad_i32_i24 %0, %1, %2, %3"
                    : "=v"(key) : "v"(ci), "s"(1024), "v"(e0));
                const int a0 = aK[mf][r];
                int t1 = min(a0, key);
                int med;
                asm("v_med3_i32 %0, %1, %2, %3"
                    : "=v"(med) : "v"(a0), "v"(bK[mf][r]), "v"(key));
                bK[mf][r] = med;
                aK[mf][r] = t1;
            }
        }
#pragma unroll
        for (int mf = 0; mf < NMF; ++mf) {
#pragma unroll
            for (int r = 0; r < 4; ++r) {
                int ci = (int)ccB[mf][r];
                int key;
                asm("v_mad_i32_i24 %0, %1, %2, %3"
                    : "=v"(key) : "v"(ci), "s"(1024), "v"(e1));
                const int a0 = aK[mf][r];
                int t1 = min(a0, key);
                int med;
                asm("v_med3_i32 %0, %1, %2, %3"
                    : "=v"(med) : "v"(a0), "v"(bK[mf][r]), "v"(key));
                bK[mf][r] = med;
                aK[mf][r] = t1;
            }
        }

        cB0a = nB0a; cB1a = nB1a; cB0b = nB0b; cB1b = nB1b;
        s2c0 = s2n0; s2c1 = s2n1;
    }

    // ---- phase B: resolve argmin per token (16-lane groups) ----
#pragma unroll
    for (int mf = 0; mf < NMF; ++mf) {
#pragma unroll
        for (int r = 0; r < 4; ++r) {
            const int a0 = aK[mf][r], b0 = bK[mf][r];
            int A = a0, B = b0;
#pragma unroll
            for (int off = 1; off < 16; off <<= 1) {
                int A2 = __shfl_xor(A, off);
                int B2 = __shfl_xor(B, off);
                int lo = min(A, A2), hi = max(A, A2);
                B = min(min(B, B2), hi);
                A = lo;
            }
            int winner = A & 1023;
            if (B - A <= WKEY) {  // contested: exact fp32 re-check of candidates
                const int t = blockTok + wv * 64 + mf * 16 + quad * 4 + r;
                float dbest = 3.4e38f;
                int ibest = 1 << 30;
                if (a0 <= A + WKEY) {
                    int e = a0 & 1023;
                    float d = exact_dist(z, emb, t, e);
                    if (d < dbest || (d == dbest && e < ibest)) { dbest = d; ibest = e; }
                }
                if (b0 <= A + WKEY) {
                    int e = b0 & 1023;
                    float d = exact_dist(z, emb, t, e);
                    if (d < dbest || (d == dbest && e < ibest)) { dbest = d; ibest = e; }
                }
#pragma unroll
                for (int off = 1; off < 16; off <<= 1) {
                    float d2 = __shfl_xor(dbest, off);
                    int i2 = __shfl_xor(ibest, off);
                    if (d2 < dbest || (d2 == dbest && i2 < ibest)) { dbest = d2; ibest = i2; }
                }
                winner = ibest;
            }
            if (col == 0) idx_lds[wv * 64 + mf * 16 + quad * 4 + r] = winner;
        }
    }

    __syncthreads();

    // ---- outputs ----
    idx_out[blockTok + tid] = (float)idx_lds[tid];
    const float4* emb_f4 = (const float4*)emb;
    float4* zq_f4 = (float4*)zq_out;
#pragma unroll
    for (int i = 0; i < MBLK * 16 / TPB; ++i) {  // 16 iters
        int item = tid + i * TPB;
        int tl = item >> 4, f4 = item & 15;
        int wi = idx_lds[tl];
        zq_f4[(size_t)(blockTok + tl) * 16 + f4] = emb_f4[(size_t)wi * 16 + f4];
    }
}

extern "C" void kernel_launch(void* const* d_in, const int* in_sizes, int n_in,
                              void* d_out, int out_size, void* d_ws, size_t ws_size,
                              hipStream_t stream) {
    const float* z = (const float*)d_in[0];
    const float* emb = (const float*)d_in[1];
    float* out = (float*)d_out;
    float* zq = out;                       // 131072*64 floats
    float* idx = out + (size_t)NTOK * ED;  // 131072 floats

    // ws layout: s2s (4KB) | bfH (128KB)
    char* ws = (char*)d_ws;
    float* s2s = (float*)ws;
    unsigned short* bfH = (unsigned short*)(ws + 4096);

    vq_prep<<<64, 128, 0, stream>>>(emb, bfH, s2s);
    vq_main<<<NTOK / MBLK, TPB, 0, stream>>>(z, emb, bfH, s2s, zq, idx);
}

// Round 12
// 129.416 us; speedup vs baseline: 1.1066x; 1.0038x over previous
//
#include <hip/hip_runtime.h>

typedef short short8 __attribute__((ext_vector_type(8)));
typedef float f32x4 __attribute__((ext_vector_type(4)));

#define NTOK (8 * 16 * 32 * 32)  // 131072 tokens
#define NE 1024
#define ED 64
#define TPB 256
#define MBLK 256                 // tokens per block = 4 waves x 64
#define NMF 4                    // m-frags per wave (64 tokens)
#define WKEY (1 << 19)           // candidate window: 7.8e-3 in dist units
#define SCALE (-131072.0f)       // -2^17: exact po2 scale — applied to B ONLY

__device__ __forceinline__ unsigned short bf16_rtne(float f) {
    unsigned u = __float_as_uint(f);
    return (unsigned short)((u + 0x7FFFu + ((u >> 16) & 1u)) >> 16);
}

// EXACT distance — identical structure/order to the R1 kernel (absmax 0 vs numpy).
__device__ float exact_dist(const float* __restrict__ z, const float* __restrict__ emb,
                            int t, int e) {
    const float* zt = z + (size_t)t * ED;
    const float* ep = emb + (size_t)e * ED;
    float r0 = 0.f, r1 = 0.f, r2 = 0.f, r3 = 0.f;
    float r4 = 0.f, r5 = 0.f, r6 = 0.f, r7 = 0.f;
    for (int d = 0; d < ED; d += 8) {
        r0 += zt[d + 0] * zt[d + 0];
        r1 += zt[d + 1] * zt[d + 1];
        r2 += zt[d + 2] * zt[d + 2];
        r3 += zt[d + 3] * zt[d + 3];
        r4 += zt[d + 4] * zt[d + 4];
        r5 += zt[d + 5] * zt[d + 5];
        r6 += zt[d + 6] * zt[d + 6];
        r7 += zt[d + 7] * zt[d + 7];
    }
    float s1 = ((r0 + r1) + (r2 + r3)) + ((r4 + r5) + (r6 + r7));
    float q0 = 0.f, q1 = 0.f, q2 = 0.f, q3 = 0.f;
    float q4 = 0.f, q5 = 0.f, q6 = 0.f, q7 = 0.f;
    for (int d = 0; d < ED; d += 8) {
        float v0 = ep[d + 0], v1 = ep[d + 1], v2 = ep[d + 2], v3 = ep[d + 3];
        float v4 = ep[d + 4], v5 = ep[d + 5], v6 = ep[d + 6], v7 = ep[d + 7];
        q0 += v0 * v0; q1 += v1 * v1; q2 += v2 * v2; q3 += v3 * v3;
        q4 += v4 * v4; q5 += v5 * v5; q6 += v6 * v6; q7 += v7 * v7;
    }
    float s2 = ((q0 + q1) + (q2 + q3)) + ((q4 + q5) + (q6 + q7));
    float a0 = 0.f, a1 = 0.f, a2 = 0.f, a3 = 0.f;
    for (int d = 0; d < ED; d += 4) {
        a0 = fmaf(zt[d + 0], ep[d + 0], a0);
        a1 = fmaf(zt[d + 1], ep[d + 1], a1);
        a2 = fmaf(zt[d + 2], ep[d + 2], a2);
        a3 = fmaf(zt[d + 3], ep[d + 3], a3);
    }
    float g = (a0 + a1) + (a2 + a3);
    return (s1 + s2) - 2.0f * g;
}

// ---- prep: B-fragments (bf16 HI only, -2^17-scaled, MFMA order) + scaled s2 ----
__global__ __launch_bounds__(128) void vq_prep(
    const float* __restrict__ emb,
    unsigned short* __restrict__ bfH,
    float* __restrict__ s2s)
{
    const int f = blockIdx.x * 128 + threadIdx.x;  // 0..8191 fragment id
    const int col = f & 15;
    const int quad = (f >> 4) & 3;
    const int kb = (f >> 6) & 1;
    const int nt = f >> 7;
    const int e = nt * 16 + col;
    const int k0 = kb * 32 + quad * 8;

    const float* p = emb + (size_t)e * ED + k0;
    float4 v0 = *(const float4*)p;
    float4 v1 = *(const float4*)(p + 4);
    float vs[8] = {v0.x, v0.y, v0.z, v0.w, v1.x, v1.y, v1.z, v1.w};
    short8 h;
#pragma unroll
    for (int j = 0; j < 8; ++j) {
        float x = vs[j] * SCALE;              // exact po2 scaling (B side only!)
        h[j] = (short)bf16_rtne(x);
    }
    *(short8*)&bfH[(size_t)f * 8] = h;

    if (f < 4096) {
        const int row = f >> 2;
        const float4* rp = (const float4*)(emb + (size_t)row * ED + (f & 3) * 16);
        float4 a = rp[0], b = rp[1], c = rp[2], d = rp[3];
        float s = a.x * a.x + a.y * a.y + a.z * a.z + a.w * a.w
                + b.x * b.x + b.y * b.y + b.z * b.z + b.w * b.w
                + c.x * c.x + c.y * c.y + c.z * c.z + c.w * c.w
                + d.x * d.x + d.y * d.y + d.z * d.z + d.w * d.w;
        s += __shfl_xor(s, 1);
        s += __shfl_xor(s, 2);
        if ((f & 3) == 0) s2s[row] = s * 65536.0f;
    }
}

// ---- main: R11 body + LAG-1 SOFTWARE PIPELINE on the key-update stage.
//      R11 counters (MfmaUtil 10% + VALUBusy 40% ~ sum 50%) showed the two
//      pipes ALTERNATE: cvt(cc) reads the MFMA dests immediately, so each
//      wave serializes [MFMA burst] -> [full result latency] -> [VALU burst].
//      Here the key-updates operate on ccPrev (one slice-pair old, long since
//      complete) while the current pair's MFMAs are in flight — VALU runs in
//      the MFMA shadow. Top-2 update {a'=min(a,k); b'=med3(a,b,k)} maintains
//      (min,2nd-min) under any processing order for unique keys, so deferring
//      updates is value-preserving: same keys, same WKEY, same exact recheck
//      -> absmax 0. ----
__global__ void __launch_bounds__(TPB) vq_main(
    const float* __restrict__ z,
    const float* __restrict__ emb,
    const unsigned short* __restrict__ bfH,
    const float* __restrict__ s2s_g,
    float* __restrict__ zq_out,
    float* __restrict__ idx_out)
{
    __shared__ float s2L[NE];
    __shared__ int idx_lds[MBLK];

    const int tid = threadIdx.x;
    const int lane = tid & 63;
    const int wv = __builtin_amdgcn_readfirstlane(tid >> 6);
    const int col = lane & 15;
    const int quad = lane >> 4;
    const int blockTok = blockIdx.x * MBLK;

    for (int i = tid; i < NE; i += TPB) s2L[i] = s2s_g[i];

    // ---- A-fragments: 64 tokens per wave (4 m-frags), bf16 hi only, UNSCALED ----
    short8 Ah[NMF][2];
#pragma unroll
    for (int mf = 0; mf < NMF; ++mf) {
#pragma unroll
        for (int kf = 0; kf < 2; ++kf) {
            const float* zp = z + (size_t)(blockTok + wv * 64 + mf * 16 + col) * ED
                              + kf * 32 + quad * 8;
            float4 v0 = *(const float4*)zp;
            float4 v1 = *(const float4*)(zp + 4);
            float vs[8] = {v0.x, v0.y, v0.z, v0.w, v1.x, v1.y, v1.z, v1.w};
            short8 h;
#pragma unroll
            for (int j = 0; j < 8; ++j) h[j] = (short)bf16_rtne(vs[j]);
            Ah[mf][kf] = h;
        }
    }

    int aK[NMF][4], bK[NMF][4];
#pragma unroll
    for (int mf = 0; mf < NMF; ++mf)
#pragma unroll
        for (int r = 0; r < 4; ++r) { aK[mf][r] = 0x7FFFFFFF; bK[mf][r] = 0x7FFFFFFF; }

    // B-fragment stream: per nt-slice, 128 fragments of 16B; lane's frags are
    // u4[nt*128 + lane] (k-frag 0) and u4[nt*128 + 64 + lane] (k-frag 1).
    const uint4* u4H = (const uint4*)bfH;

    // prologue: B for slices 0,1
    uint4 cB0a = u4H[lane];
    uint4 cB1a = u4H[64 + lane];
    uint4 cB0b = u4H[128 + lane];
    uint4 cB1b = u4H[192 + lane];

    __syncthreads();  // s2L ready (only barrier before the epilogue)

    float s2c0 = s2L[col];
    float s2c1 = s2L[16 + col];

    // ---- pipeline prologue: compute cc for slices 0,1 into ccP ----
    f32x4 ccPA[NMF], ccPB[NMF];
    {
        short8 BhA0 = __builtin_bit_cast(short8, cB0a);
        short8 BhA1 = __builtin_bit_cast(short8, cB1a);
        short8 BhB0 = __builtin_bit_cast(short8, cB0b);
        short8 BhB1 = __builtin_bit_cast(short8, cB1b);
        __builtin_amdgcn_s_setprio(1);
#pragma unroll
        for (int mf = 0; mf < NMF; ++mf) {
            f32x4 c0 = {s2c0, s2c0, s2c0, s2c0};
            c0 = __builtin_amdgcn_mfma_f32_16x16x32_bf16(Ah[mf][0], BhA0, c0, 0, 0, 0);
            c0 = __builtin_amdgcn_mfma_f32_16x16x32_bf16(Ah[mf][1], BhA1, c0, 0, 0, 0);
            ccPA[mf] = c0;
        }
#pragma unroll
        for (int mf = 0; mf < NMF; ++mf) {
            f32x4 c1 = {s2c1, s2c1, s2c1, s2c1};
            c1 = __builtin_amdgcn_mfma_f32_16x16x32_bf16(Ah[mf][0], BhB0, c1, 0, 0, 0);
            c1 = __builtin_amdgcn_mfma_f32_16x16x32_bf16(Ah[mf][1], BhB1, c1, 0, 0, 0);
            ccPB[mf] = c1;
        }
        __builtin_amdgcn_s_setprio(0);
    }
    // load B + s2 for slices 2,3
    cB0a = u4H[256 + lane];
    cB1a = u4H[256 + 64 + lane];
    cB0b = u4H[384 + lane];
    cB1b = u4H[384 + 64 + lane];
    s2c0 = s2L[32 + col];
    s2c1 = s2L[48 + col];

    // ---- steady state: MFMA(nt,nt+1) || key-update(nt-2,nt-1) ----
    for (int nt = 2; nt < 64; nt += 2) {
        // prefetch slices nt+2, nt+3 (wrap: redundant, never consumed)
        const int nb2 = (((nt + 2) & 63) << 7) + lane;
        const int nb3 = (((nt + 3) & 63) << 7) + lane;
        uint4 nB0a = u4H[nb2];
        uint4 nB1a = u4H[nb2 + 64];
        uint4 nB0b = u4H[nb3];
        uint4 nB1b = u4H[nb3 + 64];
        float s2n0 = s2L[((nt + 2) & 63) * 16 + col];
        float s2n1 = s2L[((nt + 3) & 63) * 16 + col];

        short8 BhA0 = __builtin_bit_cast(short8, cB0a);
        short8 BhA1 = __builtin_bit_cast(short8, cB1a);
        short8 BhB0 = __builtin_bit_cast(short8, cB0b);
        short8 BhB1 = __builtin_bit_cast(short8, cB1b);

        f32x4 ccCA[NMF], ccCB[NMF];
        __builtin_amdgcn_s_setprio(1);
#pragma unroll
        for (int mf = 0; mf < NMF; ++mf) {
            f32x4 c0 = {s2c0, s2c0, s2c0, s2c0};
            c0 = __builtin_amdgcn_mfma_f32_16x16x32_bf16(Ah[mf][0], BhA0, c0, 0, 0, 0);
            c0 = __builtin_amdgcn_mfma_f32_16x16x32_bf16(Ah[mf][1], BhA1, c0, 0, 0, 0);
            ccCA[mf] = c0;
        }
#pragma unroll
        for (int mf = 0; mf < NMF; ++mf) {
            f32x4 c1 = {s2c1, s2c1, s2c1, s2c1};
            c1 = __builtin_amdgcn_mfma_f32_16x16x32_bf16(Ah[mf][0], BhB0, c1, 0, 0, 0);
            c1 = __builtin_amdgcn_mfma_f32_16x16x32_bf16(Ah[mf][1], BhB1, c1, 0, 0, 0);
            ccCB[mf] = c1;
        }
        __builtin_amdgcn_s_setprio(0);

        // key-updates for the PREVIOUS pair (slices nt-2, nt-1): ccP complete
        const int e0 = (nt - 2) * 16 + col;
        const int e1 = e0 + 16;
#pragma unroll
        for (int mf = 0; mf < NMF; ++mf) {
#pragma unroll
            for (int r = 0; r < 4; ++r) {
                int ci = (int)ccPA[mf][r];
                int key;
                asm("v_mad_i32_i24 %0, %1, %2, %3"
                    : "=v"(key) : "v"(ci), "s"(1024), "v"(e0));
                const int a0 = aK[mf][r];
                int t1 = min(a0, key);
                int med;
                asm("v_med3_i32 %0, %1, %2, %3"
                    : "=v"(med) : "v"(a0), "v"(bK[mf][r]), "v"(key));
                bK[mf][r] = med;
                aK[mf][r] = t1;
            }
        }
#pragma unroll
        for (int mf = 0; mf < NMF; ++mf) {
#pragma unroll
            for (int r = 0; r < 4; ++r) {
                int ci = (int)ccPB[mf][r];
                int key;
                asm("v_mad_i32_i24 %0, %1, %2, %3"
                    : "=v"(key) : "v"(ci), "s"(1024), "v"(e1));
                const int a0 = aK[mf][r];
                int t1 = min(a0, key);
                int med;
                asm("v_med3_i32 %0, %1, %2, %3"
                    : "=v"(med) : "v"(a0), "v"(bK[mf][r]), "v"(key));
                bK[mf][r] = med;
                aK[mf][r] = t1;
            }
        }

        // rotate pipeline state
#pragma unroll
        for (int mf = 0; mf < NMF; ++mf) { ccPA[mf] = ccCA[mf]; ccPB[mf] = ccCB[mf]; }
        cB0a = nB0a; cB1a = nB1a; cB0b = nB0b; cB1b = nB1b;
        s2c0 = s2n0; s2c1 = s2n1;
    }

    // ---- pipeline epilogue: key-updates for slices 62,63 ----
    {
        const int e0 = 62 * 16 + col;
        const int e1 = e0 + 16;
#pragma unroll
        for (int mf = 0; mf < NMF; ++mf) {
#pragma unroll
            for (int r = 0; r < 4; ++r) {
                int ci = (int)ccPA[mf][r];
                int key;
                asm("v_mad_i32_i24 %0, %1, %2, %3"
                    : "=v"(key) : "v"(ci), "s"(1024), "v"(e0));
                const int a0 = aK[mf][r];
                int t1 = min(a0, key);
                int med;
                asm("v_med3_i32 %0, %1, %2, %3"
                    : "=v"(med) : "v"(a0), "v"(bK[mf][r]), "v"(key));
                bK[mf][r] = med;
                aK[mf][r] = t1;
            }
        }
#pragma unroll
        for (int mf = 0; mf < NMF; ++mf) {
#pragma unroll
            for (int r = 0; r < 4; ++r) {
                int ci = (int)ccPB[mf][r];
                int key;
                asm("v_mad_i32_i24 %0, %1, %2, %3"
                    : "=v"(key) : "v"(ci), "s"(1024), "v"(e1));
                const int a0 = aK[mf][r];
                int t1 = min(a0, key);
                int med;
                asm("v_med3_i32 %0, %1, %2, %3"
                    : "=v"(med) : "v"(a0), "v"(bK[mf][r]), "v"(key));
                bK[mf][r] = med;
                aK[mf][r] = t1;
            }
        }
    }

    // ---- phase B: resolve argmin per token (16-lane groups) ----
#pragma unroll
    for (int mf = 0; mf < NMF; ++mf) {
#pragma unroll
        for (int r = 0; r < 4; ++r) {
            const int a0 = aK[mf][r], b0 = bK[mf][r];
            int A = a0, B = b0;
#pragma unroll
            for (int off = 1; off < 16; off <<= 1) {
                int A2 = __shfl_xor(A, off);
                int B2 = __shfl_xor(B, off);
                int lo = min(A, A2), hi = max(A, A2);
                B = min(min(B, B2), hi);
                A = lo;
            }
            int winner = A & 1023;
            if (B - A <= WKEY) {  // contested: exact fp32 re-check of candidates
                const int t = blockTok + wv * 64 + mf * 16 + quad * 4 + r;
                float dbest = 3.4e38f;
                int ibest = 1 << 30;
                if (a0 <= A + WKEY) {
                    int e = a0 & 1023;
                    float d = exact_dist(z, emb, t, e);
                    if (d < dbest || (d == dbest && e < ibest)) { dbest = d; ibest = e; }
                }
                if (b0 <= A + WKEY) {
                    int e = b0 & 1023;
                    float d = exact_dist(z, emb, t, e);
                    if (d < dbest || (d == dbest && e < ibest)) { dbest = d; ibest = e; }
                }
#pragma unroll
                for (int off = 1; off < 16; off <<= 1) {
                    float d2 = __shfl_xor(dbest, off);
                    int i2 = __shfl_xor(ibest, off);
                    if (d2 < dbest || (d2 == dbest && i2 < ibest)) { dbest = d2; ibest = i2; }
                }
                winner = ibest;
            }
            if (col == 0) idx_lds[wv * 64 + mf * 16 + quad * 4 + r] = winner;
        }
    }

    __syncthreads();

    // ---- outputs ----
    idx_out[blockTok + tid] = (float)idx_lds[tid];
    const float4* emb_f4 = (const float4*)emb;
    float4* zq_f4 = (float4*)zq_out;
#pragma unroll
    for (int i = 0; i < MBLK * 16 / TPB; ++i) {  // 16 iters
        int item = tid + i * TPB;
        int tl = item >> 4, f4 = item & 15;
        int wi = idx_lds[tl];
        zq_f4[(size_t)(blockTok + tl) * 16 + f4] = emb_f4[(size_t)wi * 16 + f4];
    }
}

extern "C" void kernel_launch(void* const* d_in, const int* in_sizes, int n_in,
                              void* d_out, int out_size, void* d_ws, size_t ws_size,
                              hipStream_t stream) {
    const float* z = (const float*)d_in[0];
    const float* emb = (const float*)d_in[1];
    float* out = (float*)d_out;
    float* zq = out;                       // 131072*64 floats
    float* idx = out + (size_t)NTOK * ED;  // 131072 floats

    // ws layout: s2s (4KB) | bfH (128KB)
    char* ws = (char*)d_ws;
    float* s2s = (float*)ws;
    unsigned short* bfH = (unsigned short*)(ws + 4096);

    vq_prep<<<64, 128, 0, stream>>>(emb, bfH, s2s);
    vq_main<<<NTOK / MBLK, TPB, 0, stream>>>(z, emb, bfH, s2s, zq, idx);
}